// Round 1
// baseline (138.240 us; speedup 1.0000x reference)
//
#include <hip/hip_runtime.h>

// BPMLL loss, B=16384 rows, L=1024 cols, f32 c / i32 y in, scalar f32 out.
// Per row: pos = sum y*exp(-c); neg = sum (1-y)*exp(c);
// loss = pos*neg/(sum_y*(L-sum_y)); out = mean over rows.
//
// R6 theory: top-5 dispatches are ALL 256MiB harness poison fills at 6.5TB/s
// (82% peak write) -> memory system is NOT capped at 3.2TB/s. Main kernel's
// 41us = 134MB read + ~134MB hidden dirty-line writeback: the 256MiB ws
// poison leaves L2+L3 fully dirty each iteration, and allocating reads evict
// 1:1 -> 268MB true HBM traffic @6.3TB/s = 42.6us ~= measured. R5's
// __builtin_nontemporal_load only sets nt (neutral). This round: full bypass
// reads (sc0 sc1 nt) via inline asm -> no allocation -> no writeback, plus
// 3x TLP (1 row/wave, 4096 blocks, ~24 waves/CU) to cover bypass latency.
// Manual s_waitcnt vmcnt(0) + sched_barrier(0) required (rule #18: compiler
// does not track asm loads; "memory" clobber does not order VALU consumers).

#define NROWS 16384
#define NCOLS 1024
#define WPB 4                      // waves per block (256 threads)
#define NBLOCKS (NROWS / WPB)      // 4096 blocks, one row per wave

typedef float vf4 __attribute__((ext_vector_type(4)));
typedef int vi4 __attribute__((ext_vector_type(4)));

__device__ __forceinline__ void elem(float cv, int yv,
                                     float& pos, float& neg, float& cnt) {
    float t = __expf(yv ? -cv : cv);   // one transcendental per element
    pos += yv ? t : 0.f;
    neg += yv ? 0.f : t;
    cnt += (float)yv;
}

__device__ __forceinline__ void consume4(const vf4& cv, const vi4& yv,
                                         float& pos, float& neg, float& cnt) {
    elem(cv.x, yv.x, pos, neg, cnt);
    elem(cv.y, yv.y, pos, neg, cnt);
    elem(cv.z, yv.z, pos, neg, cnt);
    elem(cv.w, yv.w, pos, neg, cnt);
}

// Streaming load: sc0 sc1 nt = device-scope, non-temporal, no L1/L2
// allocation. Volatile asm: ordered vs the waitcnt asm below; data arrives
// only after s_waitcnt vmcnt(0).
#define STREAM_LD(dst, addr, off_str)                                  \
    asm volatile("global_load_dwordx4 %0, %1, off" off_str " sc0 sc1 nt" \
                 : "=v"(dst) : "v"(addr))

__global__ __launch_bounds__(256, 6) void bpmll_rows_kernel(
    const float* __restrict__ c, const int* __restrict__ y,
    float* __restrict__ partials) {
    const int wave = threadIdx.x >> 6;
    const int lane = threadIdx.x & 63;
    const int row = blockIdx.x * WPB + wave;   // one 4KB row per wave

    // Lane l owns bytes [16l,16l+16) at row-relative strides of 1KB.
    const char* cp = (const char*)(c + (size_t)row * NCOLS) + lane * 16;
    const char* yp = (const char*)(y + (size_t)row * NCOLS) + lane * 16;

    vf4 cb0, cb1, cb2, cb3;
    vi4 yb0, yb1, yb2, yb3;
    STREAM_LD(cb0, cp, "");
    STREAM_LD(cb1, cp, " offset:1024");
    STREAM_LD(cb2, cp, " offset:2048");
    STREAM_LD(cb3, cp, " offset:3072");
    STREAM_LD(yb0, yp, "");
    STREAM_LD(yb1, yp, " offset:1024");
    STREAM_LD(yb2, yp, " offset:2048");
    STREAM_LD(yb3, yp, " offset:3072");

    asm volatile("s_waitcnt vmcnt(0)" ::: "memory");
    __builtin_amdgcn_sched_barrier(0);  // rule #18: pin consumers after wait

    float pos = 0.f, neg = 0.f, cnt = 0.f;
    consume4(cb0, yb0, pos, neg, cnt);
    consume4(cb1, yb1, pos, neg, cnt);
    consume4(cb2, yb2, pos, neg, cnt);
    consume4(cb3, yb3, pos, neg, cnt);

#pragma unroll
    for (int off = 1; off < 64; off <<= 1) {
        pos += __shfl_xor(pos, off);
        neg += __shfl_xor(neg, off);
        cnt += __shfl_xor(cnt, off);
    }
    const float loss = (pos * neg) / (cnt * ((float)NCOLS - cnt));  // BIAS=(1,1)

    __shared__ float acc[WPB];
    if (lane == 0) acc[wave] = loss;
    __syncthreads();
    if (threadIdx.x == 0) {
        partials[blockIdx.x] =
            (acc[0] + acc[1] + acc[2] + acc[3]) * (1.0f / (float)NROWS);
    }
}

__global__ __launch_bounds__(256) void bpmll_reduce_kernel(
    const float* __restrict__ partials, float* __restrict__ out) {
    // 4096 partials, 256 threads -> 16 floats per thread, coalesced.
    float s = 0.f;
#pragma unroll
    for (int i = 0; i < 16; ++i) s += partials[threadIdx.x + 256 * i];
#pragma unroll
    for (int off = 1; off < 64; off <<= 1) s += __shfl_xor(s, off);

    __shared__ float smem[4];
    const int lane = threadIdx.x & 63;
    const int wave = threadIdx.x >> 6;
    if (lane == 0) smem[wave] = s;
    __syncthreads();
    if (threadIdx.x == 0) out[0] = smem[0] + smem[1] + smem[2] + smem[3];
}

extern "C" void kernel_launch(void* const* d_in, const int* in_sizes, int n_in,
                              void* d_out, int out_size, void* d_ws, size_t ws_size,
                              hipStream_t stream) {
    const float* c = (const float*)d_in[0];
    const int* y = (const int*)d_in[1];
    float* partials = (float*)d_ws;   // NBLOCKS floats = 16 KiB scratch
    float* out = (float*)d_out;

    bpmll_rows_kernel<<<NBLOCKS, 256, 0, stream>>>(c, y, partials);
    bpmll_reduce_kernel<<<1, 256, 0, stream>>>(partials, out);
}